// Round 16
// baseline (2961.176 us; speedup 1.0000x reference)
//
#include <hip/hip_runtime.h>
#include <hip/hip_bf16.h>

#define SEQ   256
#define BATCH 64
#define HID   1024
#define EMBD  512
#define VOCAB 128
#define G4    4096
#define HBS   (BATCH * HID)      // 65536 elems per ring slot (128 KB bf16)

typedef short bf16x8_t __attribute__((ext_vector_type(8)));
typedef float f32x4_t  __attribute__((ext_vector_type(4)));
using bf16 = __hip_bfloat16;

__device__ __forceinline__ float sigm(float v) { return 1.f / (1.f + expf(-v)); }

// write-through stores (visible at MALL; readers use normal cached loads —
// safe because every ring address is written exactly once per launch)
__device__ __forceinline__ void cstore2(void* p, unsigned short d) {
    asm volatile("global_store_short %0, %1, off sc0 sc1" :: "v"(p), "v"(d) : "memory");
}
__device__ __forceinline__ void cstore4(void* p, unsigned d) {
    asm volatile("global_store_dword %0, %1, off sc0 sc1" :: "v"(p), "v"(d) : "memory");
}

// ---------------- casts ----------------
__global__ void cast_f32_bf16(const float* __restrict__ src, bf16* __restrict__ dst, int n) {
    int i = blockIdx.x * blockDim.x + threadIdx.x;
    int stride = gridDim.x * blockDim.x;
    for (; i < n; i += stride) dst[i] = __float2bfloat16(src[i]);
}

// ---------------- init: ring slot 0 + flags ----------------
__global__ void init_all(const float* __restrict__ h0,
                         bf16* __restrict__ r0, bf16* __restrict__ r1,
                         unsigned* __restrict__ flags) {
    int i = blockIdx.x * blockDim.x + threadIdx.x;
    if (i < 1024) flags[i] = 0u;
    int stride = gridDim.x * blockDim.x;
    for (int k = i; k < HBS; k += stride) {
        r0[k] = __float2bfloat16(h0[k]);
        r1[k] = __float2bfloat16(h0[HBS + k]);
    }
}

// ---------------- E = emb @ Wih0.T + b0   [VOCAB][G4] f32 (validated r2-r15) -
__global__ __launch_bounds__(256) void emb_gemm(
    const bf16* __restrict__ emb_bf, const bf16* __restrict__ Wih0_bf,
    const float* __restrict__ b0, float* __restrict__ E) {
    __shared__ float pb[4 * 128 * 17];
    const int tid = threadIdx.x, l = tid & 63, w = tid >> 6;
    const int lm = l & 15, k8 = (l >> 4) << 3;
    const int colbase = blockIdx.x * 16;
    const int gcol = colbase + lm;
    const int kq = w * 128;

    f32x4_t acc[8];
    #pragma unroll
    for (int rt = 0; rt < 8; ++rt) acc[rt] = f32x4_t{0.f, 0.f, 0.f, 0.f};
    bf16x8_t bf[4];
    #pragma unroll
    for (int k = 0; k < 4; ++k)
        bf[k] = *reinterpret_cast<const bf16x8_t*>(Wih0_bf + gcol * EMBD + kq + k * 32 + k8);
    #pragma unroll
    for (int k = 0; k < 4; ++k)
        #pragma unroll
        for (int rt = 0; rt < 8; ++rt) {
            bf16x8_t a = *reinterpret_cast<const bf16x8_t*>(
                emb_bf + (rt * 16 + lm) * EMBD + kq + k * 32 + k8);
            acc[rt] = __builtin_amdgcn_mfma_f32_16x16x32_bf16(a, bf[k], acc[rt], 0, 0, 0);
        }
    const int r0 = (l >> 4) << 2;
    #pragma unroll
    for (int rt = 0; rt < 8; ++rt)
        #pragma unroll
        for (int r = 0; r < 4; ++r)
            pb[(w * 128 + rt * 16 + r0 + r) * 17 + lm] = acc[rt][r];
    __syncthreads();
    #pragma unroll
    for (int i = 0; i < 8; ++i) {
        int p = tid + i * 256;
        int m = p >> 4, cc = p & 15;
        float g = pb[(0 * 128 + m) * 17 + cc] + pb[(1 * 128 + m) * 17 + cc]
                + pb[(2 * 128 + m) * 17 + cc] + pb[(3 * 128 + m) * 17 + cc];
        E[m * G4 + colbase + cc] = g + b0[colbase + cc];
    }
}

// ---- per-WAVE poll: consumer wave w needs rows w*16..w*16+15 (full K), which
//      wave w of ALL 128 producer WGs writes. Lane i polls 2 flags; __all. ----
__device__ __forceinline__ void pollwave(const unsigned* fbase, unsigned target, int l) {
    const unsigned* p0 = fbase + (l & 63);
    const unsigned* p1 = fbase + 64 + (l & 63);
    bool ok = (__hip_atomic_load(p0, __ATOMIC_RELAXED, __HIP_MEMORY_SCOPE_AGENT) >= target)
           && (__hip_atomic_load(p1, __ATOMIC_RELAXED, __HIP_MEMORY_SCOPE_AGENT) >= target);
    while (!__all((int)ok)) {
        __builtin_amdgcn_s_sleep(1);
        ok = (__hip_atomic_load(p0, __ATOMIC_RELAXED, __HIP_MEMORY_SCOPE_AGENT) >= target)
          && (__hip_atomic_load(p1, __ATOMIC_RELAXED, __HIP_MEMORY_SCOPE_AGENT) >= target);
    }
}

// ---- batched A-frag load: 32 x 16B direct-to-register, ONE RTT (r10 pattern,
//      register destination). Lane holds row w*16+lm, k = kc*32 + lk*8. ----
__device__ __forceinline__ void load_av(const bf16* arow, bf16x8_t (&av)[32]) {
    #pragma unroll
    for (int kc = 0; kc < 32; ++kc)
        av[kc] = *reinterpret_cast<const bf16x8_t*>(arow + kc * 32);
    asm volatile("s_waitcnt vmcnt(0)" ::: "memory");
    __builtin_amdgcn_sched_barrier(0);
}

// ---- full-K M-split GEMM: A from regs, W from LDS (r9 layout/swizzle) -------
__device__ __forceinline__ void gemm_m16(const char* Wbase, const bf16x8_t (&av)[32],
                                         int lm, int lk, f32x4_t (&acc)[2]) {
    const int swz = (lm & 7) << 4;
    #pragma unroll
    for (int kc = 0; kc < 32; ++kc) {
        const int kb = (kc * 64 + lk * 16) ^ swz;
        bf16x8_t b0 = *reinterpret_cast<const bf16x8_t*>(Wbase + lm * 2048 + kb);
        bf16x8_t b1 = *reinterpret_cast<const bf16x8_t*>(Wbase + (16 + lm) * 2048 + kb);
        acc[0] = __builtin_amdgcn_mfma_f32_16x16x32_bf16(av[kc], b0, acc[0], 0, 0, 0);
        acc[1] = __builtin_amdgcn_mfma_f32_16x16x32_bf16(av[kc], b1, acc[1], 0, 0, 0);
    }
}

// ---------------- persistent 2-group pipelined LSTM, wave-autonomous ---------
// GRP0 (wg   0..127): L0; s=0..255; r0[s] -> r0[s+1]; flag[0|w*128+gl] = s+1
// GRP1 (wg 128..255): L1; s=1..256; h: r1[s-1] -> r1[s]; flag[512|...] = s;
//      x-gate(s+1) computed POST-FLAG (r15 carried-acc pipelining).
// M-split: wave w owns rows w*16..w*16+15, all 32 gate-cols, full K.
// acc[2] per lane = final gates -> NO pbuf, NO block barriers in the loop.
// Act: lane lm holds secs {lm>>3, 2+(lm>>3)} for h-col hb+(lm&7); shfl_xor(8)
// gathers the partner's 2 sections; lanes lm<8 do the 4-row c/h update.
template<int GRP>
__device__ __forceinline__ void run_layer(
    const int* __restrict__ x,
    const bf16* __restrict__ Wx, const bf16* __restrict__ Wh,
    const float* __restrict__ E, const float* __restrict__ b1,
    const float* __restrict__ c0,
    bf16* __restrict__ rSelf, const bf16* __restrict__ rOther,
    unsigned* __restrict__ flags, float* __restrict__ out,
    char* __restrict__ Wlds, int tid, int wg)
{
    const int gl = wg & 127;
    const int hb = gl * 8;                       // 8 h-cols per WG
    const int l  = tid & 63, w = tid >> 6;       // wave = M-group (16 rows)
    const int lm = l & 15, lk = l >> 4;

    // ---- one-time W staging (r9 layout: LDS row r <-> gate-col (r>>3)*HID+hb+(r&7),
    //      byte-swizzle ^(row&7)<<4). GRP0: Wh at 0. GRP1: Wx at 0, Wh at 64KB. ----
    {
        const bf16* wsrc0 = (GRP == 0) ? Wh : Wx;
        #pragma unroll 4
        for (int i = 0; i < 16; ++i) {
            int chunk = tid + i * 256;           // [0, 4096) 16B chunks
            int row = chunk >> 7, cb = chunk & 127;
            int gc = (row >> 3) * HID + hb + (row & 7);
            bf16x8_t v = *reinterpret_cast<const bf16x8_t*>(wsrc0 + (size_t)gc * HID + cb * 8);
            *reinterpret_cast<bf16x8_t*>(Wlds + row * 2048 + ((cb * 16) ^ ((row & 7) << 4))) = v;
        }
        if (GRP == 1) {
            #pragma unroll 4
            for (int i = 0; i < 16; ++i) {
                int chunk = tid + i * 256;
                int row = chunk >> 7, cb = chunk & 127;
                int gc = (row >> 3) * HID + hb + (row & 7);
                bf16x8_t v = *reinterpret_cast<const bf16x8_t*>(Wh + (size_t)gc * HID + cb * 8);
                *reinterpret_cast<bf16x8_t*>(Wlds + 65536 + row * 2048 + ((cb * 16) ^ ((row & 7) << 4))) = v;
            }
        }
    }
    __syncthreads();   // once; loop below is barrier-free

    const char* Wx_lds = Wlds;
    const char* Wh_lds = (GRP == 0) ? Wlds : (Wlds + 65536);

    // act mapping: lanes lm<8 own h-col hb+(lm&7), rows w*16+lk*4+{0..3}
    const int col = hb + (lm & 7);
    const int mrow0 = w * 16 + lk * 4;
    float creg[4];
    if (lm < 8) {
        #pragma unroll
        for (int r = 0; r < 4; ++r)
            creg[r] = c0[GRP * HBS + (size_t)(mrow0 + r) * HID + col];
    }
    float bias[4];
    if (GRP == 1 && lm < 8) {
        #pragma unroll
        for (int sec = 0; sec < 4; ++sec) bias[sec] = b1[sec * HID + col];
    }

    const unsigned* fA   = flags + w * 128;            // GRP0 wave-w flags
    const unsigned* fOwn = flags + GRP * 512 + w * 128;
    unsigned* fMine = (unsigned*)(flags + GRP * 512 + w * 128 + gl);

    const int s_begin = (GRP == 0) ? 0 : 1;
    const int s_end   = (GRP == 0) ? SEQ : SEQ + 1;

    f32x4_t acc[2];
    auto zacc = [&]() {
        acc[0] = f32x4_t{0.f, 0.f, 0.f, 0.f};
        acc[1] = f32x4_t{0.f, 0.f, 0.f, 0.f};
    };

    bf16x8_t av[32];

    // ---- GRP1 prologue: x-gate for step 1 (r0[1] @ Wih1) ----
    if (GRP == 1) {
        zacc();
        pollwave(fA, 1u, l);
        load_av(rOther + (size_t)1 * HBS + (size_t)(w * 16 + lm) * HID + lk * 8, av);
        gemm_m16(Wx_lds, av, lm, lk, acc);
        asm volatile("s_waitcnt lgkmcnt(0)" ::: "memory");
        __builtin_amdgcn_sched_barrier(0);
    }

    for (int s = s_begin; s < s_end; ++s) {
        // ---- E-prefetch (GRP0; static data, before the poll) ----
        float ep[4][4];
        if (GRP == 0) {
            zacc();
            if (lm < 8) {
                int xv[4];
                #pragma unroll
                for (int r = 0; r < 4; ++r) xv[r] = x[s * BATCH + mrow0 + r];
                #pragma unroll
                for (int r = 0; r < 4; ++r)
                    #pragma unroll
                    for (int sec = 0; sec < 4; ++sec)
                        ep[sec][r] = E[(size_t)xv[r] * G4 + sec * HID + col];
            }
        }

        // ---- h-phase: the recurrence chain (wave-autonomous) ----
        if (GRP == 0) {
            pollwave(fOwn, (unsigned)s, l);
            load_av(rSelf + (size_t)s * HBS + (size_t)(w * 16 + lm) * HID + lk * 8, av);
        } else {
            pollwave(fOwn, (unsigned)(s - 1), l);
            load_av(rSelf + (size_t)(s - 1) * HBS + (size_t)(w * 16 + lm) * HID + lk * 8, av);
        }
        gemm_m16(Wh_lds, av, lm, lk, acc);   // GRP1: accumulates onto x-acc

        // ---- act: shfl-gather partner sections, lanes lm<8 update 4 rows ----
        float oth0[4], oth1[4];
        #pragma unroll
        for (int r = 0; r < 4; ++r) {
            oth0[r] = __shfl_xor(acc[0][r], 8);
            oth1[r] = __shfl_xor(acc[1][r], 8);
        }
        const int wslot = (GRP == 0) ? s + 1 : s;
        if (lm < 8) {
            bf16* rw = rSelf + (size_t)wslot * HBS;
            const bool last = (GRP == 0) ? (s == SEQ - 1) : (s == SEQ);
            #pragma unroll
            for (int r = 0; r < 4; ++r) {
                // lm<8: own acc0 = sec0 (i), own acc1 = sec2 (g);
                //       partner (lm+8): acc0 = sec1 (f), acc1 = sec3 (o)
                float vi = acc[0][r], vf = oth0[r], vg = acc[1][r], vo = oth1[r];
                if (GRP == 0) { vi += ep[0][r]; vf += ep[1][r]; vg += ep[2][r]; vo += ep[3][r]; }
                else          { vi += bias[0];  vf += bias[1];  vg += bias[2];  vo += bias[3]; }
                float cn = sigm(vf) * creg[r] + sigm(vi) * tanhf(vg);
                float hn = sigm(vo) * tanhf(cn);
                creg[r] = cn;
                unsigned short hu = __builtin_bit_cast(unsigned short, __float2bfloat16(hn));
                cstore2(rw + (size_t)(mrow0 + r) * HID + col, hu);
                if (last) {
                    float* oh = out + BATCH * VOCAB + GRP * HBS;
                    float* oc = out + BATCH * VOCAB + 2 * HBS + GRP * HBS;
                    oh[(size_t)(mrow0 + r) * HID + col] = hn;
                    oc[(size_t)(mrow0 + r) * HID + col] = cn;
                }
            }
        }

        // ---- arrive: drain this wave's stores, publish per-wave flag ----
        asm volatile("s_waitcnt vmcnt(0)" ::: "memory");
        if (l == 0) cstore4(fMine, (unsigned)wslot);

        // ---- GRP1 post-flag: x-gate for s+1 (off-chain; r15 pattern) ----
        if (GRP == 1 && s + 1 < s_end) {
            zacc();
            pollwave(fA, (unsigned)(s + 1), l);   // ~instant in steady state
            load_av(rOther + (size_t)(s + 1) * HBS + (size_t)(w * 16 + lm) * HID + lk * 8, av);
            gemm_m16(Wx_lds, av, lm, lk, acc);
            asm volatile("s_waitcnt lgkmcnt(0)" ::: "memory");
            __builtin_amdgcn_sched_barrier(0);
        }
    }
}

__global__ __launch_bounds__(256, 1) void lstm_persist(
    const int* __restrict__ x,
    const bf16* __restrict__ Whh0, const bf16* __restrict__ Wih1,
    const bf16* __restrict__ Whh1,
    const float* __restrict__ E, const float* __restrict__ b1,
    const float* __restrict__ c0,
    bf16* __restrict__ r0, bf16* __restrict__ r1,
    unsigned* __restrict__ flags, float* __restrict__ out)
{
    __shared__ char Wlds[131072];   // GRP0: Whh (64KB); GRP1: Wih1 + Whh1 (128KB)
    const int tid = threadIdx.x, wg = blockIdx.x;
    if (wg < 128)
        run_layer<0>(x, nullptr, Whh0, E, nullptr, c0, r0, nullptr, flags, out,
                     Wlds, tid, wg);
    else
        run_layer<1>(x, Wih1, Whh1, E, b1, c0, r1, r0, flags, out,
                     Wlds, tid, wg);
}

// ---------------- FC head ----------------
__global__ void logits_kernel(const float* __restrict__ h, const float* __restrict__ Wfc,
                              const float* __restrict__ bfc, float* __restrict__ out) {
    int t = blockIdx.x * blockDim.x + threadIdx.x;
    if (t >= BATCH * VOCAB) return;
    int m = t >> 7, v = t & 127;
    const float4* hp = reinterpret_cast<const float4*>(h + (size_t)m * HID);
    const float4* wp = reinterpret_cast<const float4*>(Wfc + (size_t)v * HID);
    float acc = 0.f;
    #pragma unroll 4
    for (int k = 0; k < HID / 4; ++k) {
        float4 a = hp[k], w = wp[k];
        acc += a.x * w.x + a.y * w.y + a.z * w.z + a.w * w.w;
    }
    out[t] = acc + bfc[v];
}

// ---------------- launch ----------------
extern "C" void kernel_launch(void* const* d_in, const int* in_sizes, int n_in,
                              void* d_out, int out_size, void* d_ws, size_t ws_size,
                              hipStream_t stream) {
    const int*   x    = (const int*)d_in[0];
    const float* h0   = (const float*)d_in[1];
    const float* c0   = (const float*)d_in[2];
    const float* emb  = (const float*)d_in[3];
    const float* Wih0 = (const float*)d_in[4];
    const float* Whh0 = (const float*)d_in[5];
    const float* b0   = (const float*)d_in[6];
    const float* Wih1 = (const float*)d_in[7];
    const float* Whh1 = (const float*)d_in[8];
    const float* b1   = (const float*)d_in[9];
    const float* Wfc  = (const float*)d_in[10];
    const float* bfc  = (const float*)d_in[11];
    float* out = (float*)d_out;

    char* ws = (char*)d_ws;
    size_t off = 0;
    auto alloc = [&](size_t bytes) -> void* {
        void* p = ws + off;
        off += (bytes + 255) & ~(size_t)255;
        return p;
    };
    bf16*  Whh0_bf = (bf16*)alloc((size_t)G4 * HID * 2);
    bf16*  Wih1_bf = (bf16*)alloc((size_t)G4 * HID * 2);
    bf16*  Whh1_bf = (bf16*)alloc((size_t)G4 * HID * 2);
    float* E       = (float*)alloc((size_t)VOCAB * G4 * 4);
    bf16*  r0      = (bf16*)alloc((size_t)(SEQ + 1) * HBS * 2);   // 32.9 MB ring
    bf16*  r1      = (bf16*)alloc((size_t)(SEQ + 1) * HBS * 2);   // 32.9 MB ring
    unsigned* flags = (unsigned*)alloc(1024 * 4);   // [grp][wave][wg] dense
    bf16* Wih0_bf  = (bf16*)alloc((size_t)G4 * EMBD * 2);   // dedicated (no overlay)
    bf16* emb_bf   = (bf16*)alloc((size_t)VOCAB * EMBD * 2);
    (void)ws_size; (void)in_sizes; (void)n_in; (void)out_size;

    cast_f32_bf16<<<64,  256, 0, stream>>>(emb,  emb_bf,  VOCAB * EMBD);
    cast_f32_bf16<<<512, 256, 0, stream>>>(Wih0, Wih0_bf, G4 * EMBD);
    cast_f32_bf16<<<512, 256, 0, stream>>>(Whh0, Whh0_bf, G4 * HID);
    cast_f32_bf16<<<512, 256, 0, stream>>>(Wih1, Wih1_bf, G4 * HID);
    cast_f32_bf16<<<512, 256, 0, stream>>>(Whh1, Whh1_bf, G4 * HID);
    init_all<<<64, 256, 0, stream>>>(h0, r0, r1, flags);
    emb_gemm<<<G4 / 16, 256, 0, stream>>>(emb_bf, Wih0_bf, b0, E);

    lstm_persist<<<256, 256, 0, stream>>>(x, Whh0_bf, Wih1_bf, Whh1_bf,
                                          E, b1, c0, r0, r1, flags, out);

    logits_kernel<<<(BATCH * VOCAB + 255) / 256, 256, 0, stream>>>(
        out + BATCH * VOCAB + HBS, Wfc, bfc, out);
}

// Round 17
// 1891.516 us; speedup vs baseline: 1.5655x; 1.5655x over previous
//
#include <hip/hip_runtime.h>
#include <hip/hip_bf16.h>

#define SEQ   256
#define BATCH 64
#define HID   1024
#define EMBD  512
#define VOCAB 128
#define G4    4096
#define HBS   (BATCH * HID)      // 65536 elems per ring slot (128 KB bf16)

typedef short bf16x8_t __attribute__((ext_vector_type(8)));
typedef float f32x4_t  __attribute__((ext_vector_type(4)));
using bf16 = __hip_bfloat16;

__device__ __forceinline__ float sigm(float v) { return 1.f / (1.f + expf(-v)); }

// write-through 4B store (visible at MALL; readers use normal cached loads —
// safe because every ring address is written exactly once per launch)
__device__ __forceinline__ void cstore4(void* p, unsigned d) {
    asm volatile("global_store_dword %0, %1, off sc0 sc1" :: "v"(p), "v"(d) : "memory");
}

// ---------------- casts ----------------
__global__ void cast_f32_bf16(const float* __restrict__ src, bf16* __restrict__ dst, int n) {
    int i = blockIdx.x * blockDim.x + threadIdx.x;
    int stride = gridDim.x * blockDim.x;
    for (; i < n; i += stride) dst[i] = __float2bfloat16(src[i]);
}

// ---------------- init: ring slot 0 + flags ----------------
__global__ void init_all(const float* __restrict__ h0,
                         bf16* __restrict__ r0, bf16* __restrict__ r1,
                         unsigned* __restrict__ flags) {
    int i = blockIdx.x * blockDim.x + threadIdx.x;
    if (i < 512) flags[i] = 0u;
    int stride = gridDim.x * blockDim.x;
    for (int k = i; k < HBS; k += stride) {
        r0[k] = __float2bfloat16(h0[k]);
        r1[k] = __float2bfloat16(h0[HBS + k]);
    }
}

// ---------------- E = emb @ Wih0.T + b0   [VOCAB][G4] f32 (validated r2-r15) -
__global__ __launch_bounds__(256) void emb_gemm(
    const bf16* __restrict__ emb_bf, const bf16* __restrict__ Wih0_bf,
    const float* __restrict__ b0, float* __restrict__ E) {
    __shared__ float pb[4 * 128 * 17];
    const int tid = threadIdx.x, l = tid & 63, w = tid >> 6;
    const int lm = l & 15, k8 = (l >> 4) << 3;
    const int colbase = blockIdx.x * 16;
    const int gcol = colbase + lm;
    const int kq = w * 128;

    f32x4_t acc[8];
    #pragma unroll
    for (int rt = 0; rt < 8; ++rt) acc[rt] = f32x4_t{0.f, 0.f, 0.f, 0.f};
    bf16x8_t bf[4];
    #pragma unroll
    for (int k = 0; k < 4; ++k)
        bf[k] = *reinterpret_cast<const bf16x8_t*>(Wih0_bf + gcol * EMBD + kq + k * 32 + k8);
    #pragma unroll
    for (int k = 0; k < 4; ++k)
        #pragma unroll
        for (int rt = 0; rt < 8; ++rt) {
            bf16x8_t a = *reinterpret_cast<const bf16x8_t*>(
                emb_bf + (rt * 16 + lm) * EMBD + kq + k * 32 + k8);
            acc[rt] = __builtin_amdgcn_mfma_f32_16x16x32_bf16(a, bf[k], acc[rt], 0, 0, 0);
        }
    const int r0 = (l >> 4) << 2;
    #pragma unroll
    for (int rt = 0; rt < 8; ++rt)
        #pragma unroll
        for (int r = 0; r < 4; ++r)
            pb[(w * 128 + rt * 16 + r0 + r) * 17 + lm] = acc[rt][r];
    __syncthreads();
    #pragma unroll
    for (int i = 0; i < 8; ++i) {
        int p = tid + i * 256;
        int m = p >> 4, cc = p & 15;
        float g = pb[(0 * 128 + m) * 17 + cc] + pb[(1 * 128 + m) * 17 + cc]
                + pb[(2 * 128 + m) * 17 + cc] + pb[(3 * 128 + m) * 17 + cc];
        E[m * G4 + colbase + cc] = g + b0[colbase + cc];
    }
}

// ---- per-wave A staging: 64 rows x 256 K slice -> LDS via global_load_lds ----
// LDS [64 rows][512 B] linear; bank swizzle via PRE-SWIZZLED global source.
// r17 DELTA: swizzle widened from (row&7) (3-bit -> 8-way read conflict) to
// ((row&15)<<1) (4-bit into unit bits 1-4 -> exact 2-way pairing
// (lm,lk)<->(lm^1,lk^2), which is free per m136). Bijective within each row.
__device__ __forceinline__ void stage_slice(const char* slotB, char* Aregion,
                                            int kByte, int l) {
    #pragma unroll
    for (int i = 0; i < 32; ++i) {
        const int ci  = i * 64 + l;
        const int row = ci >> 5, kb = ci & 31;
        const int swz = ((row & 15) << 1) & 31;
        const char* g = slotB + row * 2048 + kByte + ((kb ^ swz) << 4);
        __builtin_amdgcn_global_load_lds(
            (const __attribute__((address_space(1))) unsigned*)g,
            (__attribute__((address_space(3))) unsigned*)(Aregion + i * 1024),
            16, 0, 0);
    }
}

// ---- W-frag batch issue (static addresses; issued BEFORE polls to hide RTT) --
__device__ __forceinline__ void issue_w(bf16x8_t (&bw)[2][8], const bf16* W,
                                        int gcol0, int gcol1, int kg, int lk) {
    #pragma unroll
    for (int nt = 0; nt < 2; ++nt) {
        const bf16* wb = W + (size_t)(nt == 0 ? gcol0 : gcol1) * HID + kg * 256 + lk * 8;
        #pragma unroll
        for (int kc = 0; kc < 8; ++kc)
            bw[nt][kc] = *reinterpret_cast<const bf16x8_t*>(wb + kc * 32);
    }
}

// ---- K-slice GEMM compute: A from LDS region, W already in regs -------------
// r17 DELTA: read swizzle matches the new stage pre-swizzle ((row&15)<<5 bytes).
__device__ __forceinline__ void gemm_compute(const char* Aregion,
                                             const bf16x8_t (&bw)[2][8],
                                             int lm, int lk, f32x4_t (&acc)[4][2]) {
    asm volatile("s_waitcnt vmcnt(0)" ::: "memory");   // A-DMA + W loads landed
    __builtin_amdgcn_sched_barrier(0);
    #pragma unroll
    for (int kc = 0; kc < 8; ++kc) {
        bf16x8_t a[4];
        #pragma unroll
        for (int mt = 0; mt < 4; ++mt) {
            const int row = mt * 16 + lm;
            a[mt] = *reinterpret_cast<const bf16x8_t*>(
                Aregion + row * 512 + ((kc * 64 + lk * 16) ^ ((row & 15) << 5)));
        }
        #pragma unroll
        for (int mt = 0; mt < 4; ++mt) {
            acc[mt][0] = __builtin_amdgcn_mfma_f32_16x16x32_bf16(a[mt], bw[0][kc], acc[mt][0], 0, 0, 0);
            acc[mt][1] = __builtin_amdgcn_mfma_f32_16x16x32_bf16(a[mt], bw[1][kc], acc[mt][1], 0, 0, 0);
        }
    }
}

// ---- PER-WAVE slice poll (validated r14/r15): wave kg consumes h-cols
//      [kg*256, kg*256+256) produced by flag indices [kg*32, kg*32+32).
__device__ __forceinline__ void pollslice(const unsigned* fbase, int kg,
                                          unsigned target, int l) {
    const unsigned* fp = fbase + kg * 32 + (l & 31);
    bool ok = (__hip_atomic_load(fp, __ATOMIC_RELAXED,
                                 __HIP_MEMORY_SCOPE_AGENT) >= target);
    while (!__all((int)ok)) {
        __builtin_amdgcn_s_sleep(1);
        ok = (__hip_atomic_load(fp, __ATOMIC_RELAXED,
                                __HIP_MEMORY_SCOPE_AGENT) >= target);
    }
}

// ---------------- persistent 2-group pipelined LSTM (r15 structure) ----------
// GRP0 (wg   0..127): L0; s=0..255; r0[s] -> r0[s+1]
// GRP1 (wg 128..255): L1; s=1..256; h: r1[s-1] -> r1[s]; x-gate for step s+1
//   computed POST-FLAG at step s (carried acc) -> x-phase off the chain.
template<int GRP>
__device__ __forceinline__ void run_layer(
    const int* __restrict__ x,
    const bf16* __restrict__ Wx, const bf16* __restrict__ Wh,
    const float* __restrict__ E, const float* __restrict__ b1,
    const float* __restrict__ c0,
    bf16* __restrict__ rSelf, const bf16* __restrict__ rOther,
    unsigned* __restrict__ flags, float* __restrict__ out,
    char* __restrict__ Abuf, float* __restrict__ pbuf, int tid, int wg)
{
    const int gl = wg & 127;
    const int hb = gl * 8;                       // 8 h-cols per WG
    const int l  = tid & 63, kg = tid >> 6;      // wave = K-slice group (256 wide)
    const int lm = l & 15, lk = l >> 4;
    char* Areg = Abuf + kg * 32768;              // wave-private 32 KB
    const int kByte = kg * 512;

    // gate columns (weight rows): tile nt covers sections 2nt + (lm>>3)  [r9-r15]
    const int gcol0 = (0 + (lm >> 3)) * HID + hb + (lm & 7);
    const int gcol1 = (2 + (lm >> 3)) * HID + hb + (lm & 7);

    // activation mapping: thread -> (row am, 2 h-cols)  [r9-r15 verbatim]
    const int am = tid >> 2, cp = tid & 3;
    const int cc0 = cp * 2, col0 = hb + cc0;
    float creg[2];
    creg[0] = c0[GRP * HBS + am * HID + col0];
    creg[1] = c0[GRP * HBS + am * HID + col0 + 1];

    const unsigned* fA = flags;                        // GRP0 flags (dense)
    const unsigned* fOwn = flags + GRP * 128;
    unsigned* fMine = (unsigned*)(fOwn + gl);

    const int s_begin = (GRP == 0) ? 0 : 1;
    const int s_end   = (GRP == 0) ? SEQ : SEQ + 1;

    f32x4_t acc[4][2];
    auto zacc = [&]() {
        #pragma unroll
        for (int mt = 0; mt < 4; ++mt) {
            acc[mt][0] = f32x4_t{0.f, 0.f, 0.f, 0.f};
            acc[mt][1] = f32x4_t{0.f, 0.f, 0.f, 0.f};
        }
    };

    // ---- GRP1 prologue: x-gate for step 1 (r0[1] @ Wih1) ----
    if (GRP == 1) {
        zacc();
        bf16x8_t bwx[2][8];
        issue_w(bwx, Wx, gcol0, gcol1, kg, lk);
        pollslice(fA, kg, 1u, l);                  // GRP0 step 0 done (no deadlock)
        stage_slice((const char*)(rOther + (size_t)1 * HBS), Areg, kByte, l);
        gemm_compute(Areg, bwx, lm, lk, acc);
        asm volatile("s_waitcnt lgkmcnt(0)" ::: "memory");
        __builtin_amdgcn_sched_barrier(0);
    }

    for (int s = s_begin; s < s_end; ++s) {
        // ---- E-prefetch (GRP0; static data, before any wait)  [r11-r15] ----
        float ep[4][2];
        if (GRP == 0) {
            const int xv = x[s * BATCH + am];
            const float* Ep = E + (size_t)xv * G4 + col0;
            #pragma unroll
            for (int sec = 0; sec < 4; ++sec) {
                ep[sec][0] = Ep[sec * HID];
                ep[sec][1] = Ep[sec * HID + 1];
            }
            zacc();
        }

        // ---- h-phase: the recurrence chain ----
        {
            bf16x8_t bw[2][8];
            issue_w(bw, Wh, gcol0, gcol1, kg, lk);
            if (GRP == 0) {
                pollslice(fOwn, kg, (unsigned)s, l);
                stage_slice((const char*)(rSelf + (size_t)s * HBS), Areg, kByte, l);
            } else {
                pollslice(fOwn, kg, (unsigned)(s - 1), l);
                stage_slice((const char*)(rSelf + (size_t)(s - 1) * HBS), Areg, kByte, l);
            }
            gemm_compute(Areg, bw, lm, lk, acc);   // GRP1: accumulates onto x-acc
        }

        // ---- 2-slot cross-wave reduction  [r10-r15 verbatim] ----
        if (kg < 2) {
            #pragma unroll
            for (int mt = 0; mt < 4; ++mt)
                #pragma unroll
                for (int nt = 0; nt < 2; ++nt)
                    #pragma unroll
                    for (int r = 0; r < 4; ++r)
                        pbuf[(kg * 64 + mt * 16 + lk * 4 + r) * 34 + nt * 16 + lm]
                            = acc[mt][nt][r];
        }
        __syncthreads();
        if (kg >= 2) {
            #pragma unroll
            for (int mt = 0; mt < 4; ++mt)
                #pragma unroll
                for (int nt = 0; nt < 2; ++nt)
                    #pragma unroll
                    for (int r = 0; r < 4; ++r) {
                        float* p = &pbuf[((kg - 2) * 64 + mt * 16 + lk * 4 + r) * 34
                                         + nt * 16 + lm];
                        *p += acc[mt][nt][r];
                    }
        }
        __syncthreads();

        // ---- gate assembly + activation + ring write  [r11-r15 verbatim] ----
        float g[4][2];
        #pragma unroll
        for (int sec = 0; sec < 4; ++sec) {
            const float* p0 = &pbuf[(0 * 64 + am) * 34 + sec * 8 + cc0];
            const float* p1 = &pbuf[(1 * 64 + am) * 34 + sec * 8 + cc0];
            g[sec][0] = p0[0] + p1[0];
            g[sec][1] = p0[1] + p1[1];
        }
        if (GRP == 0) {
            #pragma unroll
            for (int sec = 0; sec < 4; ++sec) {
                g[sec][0] += ep[sec][0];
                g[sec][1] += ep[sec][1];
            }
        } else {
            #pragma unroll
            for (int sec = 0; sec < 4; ++sec) {
                g[sec][0] += b1[sec * HID + col0];
                g[sec][1] += b1[sec * HID + col0 + 1];
            }
        }

        float hn[2];
        #pragma unroll
        for (int j = 0; j < 2; ++j) {
            float si = sigm(g[0][j]);
            float sf = sigm(g[1][j]);
            float tg = tanhf(g[2][j]);
            float so = sigm(g[3][j]);
            float cn = sf * creg[j] + si * tg;
            hn[j] = so * tanhf(cn);
            creg[j] = cn;
        }
        unsigned short u0 = __builtin_bit_cast(unsigned short, __float2bfloat16(hn[0]));
        unsigned short u1 = __builtin_bit_cast(unsigned short, __float2bfloat16(hn[1]));
        const int wslot = (GRP == 0) ? s + 1 : s;
        cstore4(rSelf + (size_t)wslot * HBS + am * HID + col0,
                (unsigned)u0 | ((unsigned)u1 << 16));

        const bool last = (GRP == 0) ? (s == SEQ - 1) : (s == SEQ);
        if (last) {
            float* oh = out + BATCH * VOCAB + GRP * HBS;
            float* oc = out + BATCH * VOCAB + 2 * HBS + GRP * HBS;
            oh[am * HID + col0]     = hn[0];
            oh[am * HID + col0 + 1] = hn[1];
            oc[am * HID + col0]     = creg[0];
            oc[am * HID + col0 + 1] = creg[1];
        }

        // ---- arrive: drain ring writes, then one per-WG dense flag store ----
        asm volatile("s_waitcnt vmcnt(0)" ::: "memory");
        __syncthreads();
        if (tid == 0) cstore4(fMine, (unsigned)wslot);

        // ---- GRP1 post-flag: x-gate for step s+1 (off the chain)  [r15] ----
        if (GRP == 1 && s + 1 < s_end) {
            zacc();
            bf16x8_t bwx[2][8];
            issue_w(bwx, Wx, gcol0, gcol1, kg, lk);
            pollslice(fA, kg, (unsigned)(s + 1), l);   // ~instant in steady state
            stage_slice((const char*)(rOther + (size_t)(s + 1) * HBS), Areg, kByte, l);
            gemm_compute(Areg, bwx, lm, lk, acc);
            asm volatile("s_waitcnt lgkmcnt(0)" ::: "memory");
            __builtin_amdgcn_sched_barrier(0);
        }
    }
}

__global__ __launch_bounds__(256, 1) void lstm_persist(
    const int* __restrict__ x,
    const bf16* __restrict__ Whh0, const bf16* __restrict__ Wih1,
    const bf16* __restrict__ Whh1,
    const float* __restrict__ E, const float* __restrict__ b1,
    const float* __restrict__ c0,
    bf16* __restrict__ r0, bf16* __restrict__ r1,
    unsigned* __restrict__ flags, float* __restrict__ out)
{
    __shared__ char lds[131072 + 2 * 64 * 34 * 4];   // A 128 KB + pbuf 17 KB
    char*  Abuf = lds;
    float* pbuf = (float*)(lds + 131072);
    const int tid = threadIdx.x, wg = blockIdx.x;
    if (wg < 128)
        run_layer<0>(x, nullptr, Whh0, E, nullptr, c0, r0, nullptr, flags, out,
                     Abuf, pbuf, tid, wg);
    else
        run_layer<1>(x, Wih1, Whh1, E, b1, c0, r1, r0, flags, out,
                     Abuf, pbuf, tid, wg);
}

// ---------------- FC head ----------------
__global__ void logits_kernel(const float* __restrict__ h, const float* __restrict__ Wfc,
                              const float* __restrict__ bfc, float* __restrict__ out) {
    int t = blockIdx.x * blockDim.x + threadIdx.x;
    if (t >= BATCH * VOCAB) return;
    int m = t >> 7, v = t & 127;
    const float4* hp = reinterpret_cast<const float4*>(h + (size_t)m * HID);
    const float4* wp = reinterpret_cast<const float4*>(Wfc + (size_t)v * HID);
    float acc = 0.f;
    #pragma unroll 4
    for (int k = 0; k < HID / 4; ++k) {
        float4 a = hp[k], w = wp[k];
        acc += a.x * w.x + a.y * w.y + a.z * w.z + a.w * w.w;
    }
    out[t] = acc + bfc[v];
}

// ---------------- launch ----------------
extern "C" void kernel_launch(void* const* d_in, const int* in_sizes, int n_in,
                              void* d_out, int out_size, void* d_ws, size_t ws_size,
                              hipStream_t stream) {
    const int*   x    = (const int*)d_in[0];
    const float* h0   = (const float*)d_in[1];
    const float* c0   = (const float*)d_in[2];
    const float* emb  = (const float*)d_in[3];
    const float* Wih0 = (const float*)d_in[4];
    const float* Whh0 = (const float*)d_in[5];
    const float* b0   = (const float*)d_in[6];
    const float* Wih1 = (const float*)d_in[7];
    const float* Whh1 = (const float*)d_in[8];
    const float* b1   = (const float*)d_in[9];
    const float* Wfc  = (const float*)d_in[10];
    const float* bfc  = (const float*)d_in[11];
    float* out = (float*)d_out;

    char* ws = (char*)d_ws;
    size_t off = 0;
    auto alloc = [&](size_t bytes) -> void* {
        void* p = ws + off;
        off += (bytes + 255) & ~(size_t)255;
        return p;
    };
    bf16*  Whh0_bf = (bf16*)alloc((size_t)G4 * HID * 2);
    bf16*  Wih1_bf = (bf16*)alloc((size_t)G4 * HID * 2);
    bf16*  Whh1_bf = (bf16*)alloc((size_t)G4 * HID * 2);
    float* E       = (float*)alloc((size_t)VOCAB * G4 * 4);
    bf16*  r0      = (bf16*)alloc((size_t)(SEQ + 1) * HBS * 2);   // 32.9 MB ring
    bf16*  r1      = (bf16*)alloc((size_t)(SEQ + 1) * HBS * 2);   // 32.9 MB ring
    unsigned* flags = (unsigned*)alloc(512 * 4);                  // dense: 2x128 dwords
    bf16* Wih0_bf  = (bf16*)alloc((size_t)G4 * EMBD * 2);   // dedicated (no overlay)
    bf16* emb_bf   = (bf16*)alloc((size_t)VOCAB * EMBD * 2);
    (void)ws_size; (void)in_sizes; (void)n_in; (void)out_size;

    cast_f32_bf16<<<64,  256, 0, stream>>>(emb,  emb_bf,  VOCAB * EMBD);
    cast_f32_bf16<<<512, 256, 0, stream>>>(Wih0, Wih0_bf, G4 * EMBD);
    cast_f32_bf16<<<512, 256, 0, stream>>>(Whh0, Whh0_bf, G4 * HID);
    cast_f32_bf16<<<512, 256, 0, stream>>>(Wih1, Wih1_bf, G4 * HID);
    cast_f32_bf16<<<512, 256, 0, stream>>>(Whh1, Whh1_bf, G4 * HID);
    init_all<<<64, 256, 0, stream>>>(h0, r0, r1, flags);
    emb_gemm<<<G4 / 16, 256, 0, stream>>>(emb_bf, Wih0_bf, b0, E);

    lstm_persist<<<256, 256, 0, stream>>>(x, Whh0_bf, Wih1_bf, Whh1_bf,
                                          E, b1, c0, r0, r1, flags, out);

    logits_kernel<<<(BATCH * VOCAB + 255) / 256, 256, 0, stream>>>(
        out + BATCH * VOCAB + HBS, Wfc, bfc, out);
}